// Round 1
// baseline (133.890 us; speedup 1.0000x reference)
//
#include <hip/hip_runtime.h>

#define NBATCH 4096
#define SEQ 512
#define HID 5
#define NEMB 64

__device__ __forceinline__ float fexp(float x) {
    return __builtin_amdgcn_exp2f(x * 1.4426950408889634f);
}
__device__ __forceinline__ float frcp(float x) {
    return __builtin_amdgcn_rcpf(x);
}
__device__ __forceinline__ float fsigmoid(float x) {
    return frcp(1.0f + fexp(-x));
}
__device__ __forceinline__ float ftanh(float x) {
    float ax = fabsf(x);
    float e = __builtin_amdgcn_exp2f(ax * -2.8853900817779268f); // exp(-2|x|)
    float t = (1.0f - e) * frcp(1.0f + e);
    return copysignf(t, x);
}

// broadcast value from lane ((lane & ~7) | j) within the wave (8-lane groups)
#define BCAST(v, j) __int_as_float(__builtin_amdgcn_ds_swizzle(__float_as_int(v), (((j) << 5) | 0x18)))

__global__ __launch_bounds__(64) void lstm_enc_kernel(
    const float* __restrict__ x_num, const int* __restrict__ x_cat,
    const float* __restrict__ embed, const float* __restrict__ W_ih,
    const float* __restrict__ W_hh, const float* __restrict__ b_ih,
    const float* __restrict__ b_hh, float* __restrict__ out)
{
    __shared__ float4 s_emb[NEMB];
    int tid = threadIdx.x;
    // block = 64 threads, NEMB = 64 rows of 4 floats: one row per thread
    s_emb[tid] = ((const float4*)embed)[tid];
    __syncthreads();

    int gid = blockIdx.x * 64 + tid;
    int b   = gid >> 3;         // batch element (8 lanes per element)
    int sub = tid & 7;          // lane within group
    int k   = (sub < HID) ? sub : (HID - 1);  // hidden unit (lanes 5-7 duplicate unit 4)
    bool active = (sub < HID);

    // per-thread weights: gate rows k, 5+k, 10+k, 15+k  (i,f,g,o for unit k)
    float wi[4][5], wh[4][5], bb[4];
#pragma unroll
    for (int q = 0; q < 4; ++q) {
        int g = q * HID + k;
#pragma unroll
        for (int d = 0; d < 5; ++d) {
            wi[q][d] = W_ih[g * 5 + d];
            wh[q][d] = W_hh[g * 5 + d];
        }
        bb[q] = b_ih[g] + b_hh[g];
    }

    const float4* xp = (const float4*)(x_num + (size_t)b * SEQ);
    const int4*   cp = (const int4*)(x_cat + (size_t)b * SEQ);
    float* outp = out + (size_t)b * SEQ * HID;

    float h = 0.0f, c = 0.0f;

    float4 xf = xp[0];
    int4   cf = cp[0];

    for (int t0 = 0; t0 < SEQ; t0 += 4) {
        // prefetch next chunk (clamped on last iteration; value unused then)
        int nidx = (t0 + 4 < SEQ) ? ((t0 >> 2) + 1) : ((SEQ >> 2) - 1);
        float4 xf_n = xp[nidx];
        int4   cf_n = cp[nidx];

        float xn_a[4] = {xf.x, xf.y, xf.z, xf.w};
        int   ct_a[4] = {cf.x, cf.y, cf.z, cf.w};
#pragma unroll
        for (int u = 0; u < 4; ++u) {
            // broadcast previous-step h of units 0..4 to the whole 8-lane group
            float h0 = BCAST(h, 0);
            float h1 = BCAST(h, 1);
            float h2 = BCAST(h, 2);
            float h3 = BCAST(h, 3);
            float h4 = BCAST(h, 4);
            float4 e = s_emb[ct_a[u]];
            float xn = xn_a[u];

            float gg[4];
#pragma unroll
            for (int q = 0; q < 4; ++q) {
                float acc = bb[q];
                acc = fmaf(xn,  wi[q][0], acc);
                acc = fmaf(e.x, wi[q][1], acc);
                acc = fmaf(e.y, wi[q][2], acc);
                acc = fmaf(e.z, wi[q][3], acc);
                acc = fmaf(e.w, wi[q][4], acc);
                acc = fmaf(h0, wh[q][0], acc);
                acc = fmaf(h1, wh[q][1], acc);
                acc = fmaf(h2, wh[q][2], acc);
                acc = fmaf(h3, wh[q][3], acc);
                acc = fmaf(h4, wh[q][4], acc);
                gg[q] = acc;
            }
            float iv = fsigmoid(gg[0]);
            float fv = fsigmoid(gg[1]);
            float gv = ftanh(gg[2]);
            float ov = fsigmoid(gg[3]);
            c = fv * c + iv * gv;
            h = ov * ftanh(c);
            if (active) outp[(t0 + u) * HID + k] = h;
        }
        xf = xf_n; cf = cf_n;
    }

    if (active) {
        size_t base = (size_t)NBATCH * SEQ * HID;
        out[base + (size_t)b * HID + k] = h;                            // hT
        out[base + (size_t)NBATCH * HID + (size_t)b * HID + k] = c;     // cT
    }
}

extern "C" void kernel_launch(void* const* d_in, const int* in_sizes, int n_in,
                              void* d_out, int out_size, void* d_ws, size_t ws_size,
                              hipStream_t stream) {
    const float* x_num = (const float*)d_in[0];
    const int*   x_cat = (const int*)d_in[1];
    const float* embed = (const float*)d_in[2];
    const float* W_ih  = (const float*)d_in[3];
    const float* W_hh  = (const float*)d_in[4];
    const float* b_ih  = (const float*)d_in[5];
    const float* b_hh  = (const float*)d_in[6];
    float* out = (float*)d_out;

    dim3 grid(NBATCH * 8 / 64);  // 512 blocks
    dim3 block(64);
    hipLaunchKernelGGL(lstm_enc_kernel, grid, block, 0, stream,
                       x_num, x_cat, embed, W_ih, W_hh, b_ih, b_hh, out);
}

// Round 2
// 111.876 us; speedup vs baseline: 1.1968x; 1.1968x over previous
//
#include <hip/hip_runtime.h>

#define NBATCH 4096
#define SEQ 512
#define HID 5
#define NEMB 64

__device__ __forceinline__ float fexp2(float x){ return __builtin_amdgcn_exp2f(x); }
__device__ __forceinline__ float frcp(float x){ return __builtin_amdgcn_rcpf(x); }

// broadcast value from lane ((lane & 0x18) | j) — element j of each 8-lane group
#define BCAST(v, j) __int_as_float(__builtin_amdgcn_ds_swizzle(__float_as_int(v), (((j) << 5) | 0x18)))

__global__ __launch_bounds__(64) void lstm_enc_kernel(
    const float* __restrict__ x_num, const int* __restrict__ x_cat,
    const float* __restrict__ embed, const float* __restrict__ W_ih,
    const float* __restrict__ W_hh, const float* __restrict__ b_ih,
    const float* __restrict__ b_hh, float* __restrict__ out)
{
    __shared__ float4 s_emb[NEMB];
    int tid = threadIdx.x;
    s_emb[tid] = ((const float4*)embed)[tid];
    __syncthreads();

    int gid = blockIdx.x * 64 + tid;
    int b   = gid >> 3;         // batch element (8 lanes per element)
    int sub = tid & 7;          // lane within group
    int k   = (sub < HID) ? sub : (HID - 1);
    bool active = (sub < HID);

    const float SSIG = -1.4426950408889634f;   // -log2(e): sigmoid gates
    const float STAN =  2.8853900817779268f;   //  2*log2(e): tanh gate

    // prescale weights so activations consume exp2 directly
    float wi[4][5], wh[4][5], bb[4];
#pragma unroll
    for (int q = 0; q < 4; ++q) {
        float s = (q == 2) ? STAN : SSIG;
        int g = q * HID + k;
#pragma unroll
        for (int d = 0; d < 5; ++d) {
            wi[q][d] = W_ih[g * 5 + d] * s;
            wh[q][d] = W_hh[g * 5 + d] * s;
        }
        bb[q] = (b_ih[g] + b_hh[g]) * s;
    }

    const float4* xp = (const float4*)(x_num + (size_t)b * SEQ);
    const int4*   cp = (const int4*)(x_cat + (size_t)b * SEQ);
    float* outp = out + (size_t)b * SEQ * HID + k;

    float h = 0.0f, c = 0.0f;
    // broadcast h values carried across steps (h starts at 0)
    float hb0 = 0.f, hb1 = 0.f, hb2 = 0.f, hb3 = 0.f, hb4 = 0.f;

    float4 xf = xp[0];
    int4   cf = cp[0];
    float4 ec_[4];
    ec_[0] = s_emb[cf.x]; ec_[1] = s_emb[cf.y];
    ec_[2] = s_emb[cf.z]; ec_[3] = s_emb[cf.w];

    for (int t0 = 0; t0 < SEQ; t0 += 4) {
        // prefetch next 4-step chunk (wraps harmlessly on last iter)
        int nidx = (t0 + 4 < SEQ) ? ((t0 >> 2) + 1) : 0;
        float4 xf_n = xp[nidx];
        int4   cf_n = cp[nidx];

        float xn_a[4] = {xf.x, xf.y, xf.z, xf.w};

        // xacc: bias + x + emb part for all 4 steps — off the recurrent chain
        float xa[4][4];
#pragma unroll
        for (int u = 0; u < 4; ++u) {
            float4 e = ec_[u];
#pragma unroll
            for (int q = 0; q < 4; ++q) {
                float a = fmaf(xn_a[u], wi[q][0], bb[q]);
                a = fmaf(e.x, wi[q][1], a);
                a = fmaf(e.y, wi[q][2], a);
                a = fmaf(e.z, wi[q][3], a);
                a = fmaf(e.w, wi[q][4], a);
                xa[u][q] = a;
            }
        }

#pragma unroll
        for (int u = 0; u < 4; ++u) {
            // h-part: only thing depending on the broadcast values
            float a0 = xa[u][0], a1 = xa[u][1], a2 = xa[u][2], a3 = xa[u][3];
            a0 = fmaf(hb0, wh[0][0], a0);
            a1 = fmaf(hb0, wh[1][0], a1);
            a2 = fmaf(hb0, wh[2][0], a2);
            a3 = fmaf(hb0, wh[3][0], a3);
            a0 = fmaf(hb1, wh[0][1], a0);
            a1 = fmaf(hb1, wh[1][1], a1);
            a2 = fmaf(hb1, wh[2][1], a2);
            a3 = fmaf(hb1, wh[3][1], a3);
            a0 = fmaf(hb2, wh[0][2], a0);
            a1 = fmaf(hb2, wh[1][2], a1);
            a2 = fmaf(hb2, wh[2][2], a2);
            a3 = fmaf(hb2, wh[3][2], a3);
            a0 = fmaf(hb3, wh[0][3], a0);
            a1 = fmaf(hb3, wh[1][3], a1);
            a2 = fmaf(hb3, wh[2][3], a2);
            a3 = fmaf(hb3, wh[3][3], a3);
            a0 = fmaf(hb4, wh[0][4], a0);
            a1 = fmaf(hb4, wh[1][4], a1);
            a2 = fmaf(hb4, wh[2][4], a2);
            a3 = fmaf(hb4, wh[3][4], a3);

            // activations: a0,a1,a3 prescaled by -1/ln2; a2 prescaled by 2/ln2
            float iv = frcp(1.0f + fexp2(a0));
            float fv = frcp(1.0f + fexp2(a1));
            float ov = frcp(1.0f + fexp2(a3));
            float eg = fexp2(-fabsf(a2));
            float gv = copysignf((1.0f - eg) * frcp(1.0f + eg), a2);

            c = fmaf(fv, c, iv * gv);
            float yc = c * STAN;
            float ec2 = fexp2(-fabsf(yc));
            float tc = copysignf((1.0f - ec2) * frcp(1.0f + ec2), yc);
            h = ov * tc;

            // launch next step's broadcasts immediately
            hb0 = BCAST(h, 0);
            hb1 = BCAST(h, 1);
            hb2 = BCAST(h, 2);
            hb3 = BCAST(h, 3);
            hb4 = BCAST(h, 4);

            if (active) outp[(t0 + u) * HID] = h;
        }

        // prefetch emb rows for the NEXT block (cf_n arrived by now)
        ec_[0] = s_emb[cf_n.x]; ec_[1] = s_emb[cf_n.y];
        ec_[2] = s_emb[cf_n.z]; ec_[3] = s_emb[cf_n.w];
        xf = xf_n;
    }

    if (active) {
        size_t base = (size_t)NBATCH * SEQ * HID;
        out[base + (size_t)b * HID + k] = h;                          // hT
        out[base + (size_t)NBATCH * HID + (size_t)b * HID + k] = c;   // cT
    }
}

extern "C" void kernel_launch(void* const* d_in, const int* in_sizes, int n_in,
                              void* d_out, int out_size, void* d_ws, size_t ws_size,
                              hipStream_t stream) {
    const float* x_num = (const float*)d_in[0];
    const int*   x_cat = (const int*)d_in[1];
    const float* embed = (const float*)d_in[2];
    const float* W_ih  = (const float*)d_in[3];
    const float* W_hh  = (const float*)d_in[4];
    const float* b_ih  = (const float*)d_in[5];
    const float* b_hh  = (const float*)d_in[6];
    float* out = (float*)d_out;

    dim3 grid(NBATCH * 8 / 64);  // 512 blocks
    dim3 block(64);
    hipLaunchKernelGGL(lstm_enc_kernel, grid, block, 0, stream,
                       x_num, x_cat, embed, W_ih, W_hh, b_ih, b_hh, out);
}